// Round 6
// baseline (166.542 us; speedup 1.0000x reference)
//
#include <hip/hip_runtime.h>

// Problem constants (B=4, S=2048 -> T=8192 tokens; H=1024; E=8 experts)
constexpr int kT = 8192;
constexpr int kH = 1024;
constexpr int kE = 8;
constexpr int kMaxTiles = 72;     // kT/128 + kE
constexpr int kCntStride = 32;    // pad expert counters to separate 128B cache lines

typedef short short8 __attribute__((ext_vector_type(8)));
typedef float floatx4 __attribute__((ext_vector_type(4)));

__device__ inline unsigned short f2b(float f) {
    union { float f; unsigned int u; } v; v.f = f;
    unsigned int r = v.u + 0x7FFFu + ((v.u >> 16) & 1u);  // round-to-nearest-even
    return (unsigned short)(r >> 16);
}

#define GLDS16(gp, lp)                                                                  \
    __builtin_amdgcn_global_load_lds(                                                   \
        (const __attribute__((address_space(1))) unsigned int*)(gp),                    \
        (__attribute__((address_space(3))) unsigned int*)(lp), 16, 0, 0)

// ---------------- K1: FUSED prep (R13) ----------------
// R13 post-mortem of R12: splitting trans/router into two kernels serialized two
// phases that R3's fused kernel had been overlapping (latency-bound transpose hides
// under VALU/LDS-bound router). Sum was unchanged (~37us). Re-fuse with the
// improved bodies + PARITY INTERLEAVE (odd bid = transpose, even = router) so a
// 50/50 mix of block types is resident at all times, and router at 1024 blocks x
// 8 tokens (2x parallelism; rw re-stage reads are L2-resident, near-free).
//   odd bid  -> transpose: 64k x 128n per block, f32->bf16 BEFORE LDS, [64][136]
//               bf16 with 8-B-unit XOR swizzle (store col' = c ^ 4*((r>>3)&7));
//               column reads un-swizzle with n ^ 4*(tid&7) -> 8 distinct banks.
//   even bid -> router: rw (32KB) staged once in LDS (16-B chunk-XOR swizzle,
//               R10 fix for TA-request amplification); fused convert+router:
//               lane's own float4 x feeds FMAs vs its 4 contiguous rw rows from
//               LDS; x read once coalesced, xb stored ushort4.
__global__ __launch_bounds__(256) void k_prep(const float* __restrict__ W,
                                              unsigned short* __restrict__ Wt,
                                              const float* __restrict__ x,
                                              unsigned short* __restrict__ xb,
                                              const float* __restrict__ rw,
                                              const float* __restrict__ rb,
                                              float* __restrict__ gate,
                                              int* __restrict__ idx,
                                              int* __restrict__ cnt,
                                              int* __restrict__ done) {
    __shared__ __align__(16) char smem[32768];
    int bid = blockIdx.x, tid = threadIdx.x;
    if (bid == 0 && tid < kE + 1) {              // zero padded cnt[] and done flag
        if (tid < kE) cnt[tid * kCntStride] = 0; else *done = 0;
    }
    if (bid & 1) {
        // ---- transpose path: tb in 0..1023 ----
        unsigned short (*lt)[136] = (unsigned short(*)[136])smem;
        int tb = bid >> 1;
        int e = tb >> 7, kb = (tb >> 3) & 15, nb2 = tb & 7;
        const float* Wp = W + ((size_t)e << 20) + (size_t)(kb * 64) * kH + nb2 * 128;
        int c = (tid & 31) * 4;
#pragma unroll
        for (int i = 0; i < 8; ++i) {
            int r = i * 8 + (tid >> 5);          // 0..63
            float4 v = *(const float4*)(Wp + (size_t)r * kH + c);
            int cp = c ^ (4 * ((r >> 3) & 7));   // swizzled col (8-B unit moves)
            ushort4 o;
            o.x = f2b(v.x); o.y = f2b(v.y); o.z = f2b(v.z); o.w = f2b(v.w);
            *(ushort4*)&lt[r][cp] = o;
        }
        __syncthreads();
        int k4 = (tid & 7) * 8;                  // this thread's 8-k chunk
        unsigned short* Wo = Wt + ((size_t)e << 20)
                           + (size_t)(nb2 * 128) * kH + kb * 64 + k4;
#pragma unroll
        for (int p = 0; p < 4; ++p) {
            int n = p * 32 + (tid >> 3);         // 0..127 (output row)
            int cp = n ^ (4 * (tid & 7));        // un-swizzle: (k4+i)>>3 == tid&7
            union { unsigned short u[8]; short8 s; } pk;
#pragma unroll
            for (int i = 0; i < 8; ++i) pk.u[i] = lt[k4 + i][cp];
            *(short8*)(Wo + (size_t)n * kH) = pk.s;  // 16-B store, k-contiguous
        }
        return;
    }
    // ---- router path: rid in 0..1023, 8 tokens/block (2 per wave) ----
    float* rwlds = (float*)smem;                 // 2048 16-B chunks
    int rid = bid >> 1;
    // stage rw -> LDS, chunk-XOR swizzled; global side dense (16 B/lane contiguous)
#pragma unroll
    for (int i = 0; i < 8; ++i) {
        int g = i * 256 + tid;                   // logical 16-B chunk id
        float4 v = *(const float4*)(rw + 4 * g);
        int pq = g ^ ((g >> 3) & 7);
        *(float4*)&rwlds[4 * pq] = v;
    }
    __syncthreads();
    int w = tid >> 6, lane = tid & 63;
    for (int tk = 0; tk < 2; ++tk) {
        int t = rid * 8 + w * 2 + tk;
        const float* xp = x + (size_t)t * kH;
        unsigned short* xop = xb + (size_t)t * kH;
        float pe[8];
#pragma unroll
        for (int e2 = 0; e2 < 8; ++e2) pe[e2] = 0.f;
#pragma unroll
        for (int j = 0; j < 4; ++j) {
            int h0 = j * 256 + lane * 4;
            float4 xv = *(const float4*)(xp + h0);
            ushort4 o;
            o.x = f2b(xv.x); o.y = f2b(xv.y); o.z = f2b(xv.z); o.w = f2b(xv.w);
            *(ushort4*)(xop + h0) = o;
            float xa[4] = {xv.x, xv.y, xv.z, xv.w};
#pragma unroll
            for (int cc = 0; cc < 4; ++cc) {
                int q0 = 2 * (h0 + cc);          // even chunk of rw row h
                int key = (q0 >> 3) & 7;         // = lane&7 (write-side function match)
                float4 w0 = *(const float4*)&rwlds[4 * (q0 ^ key)];
                float4 w1 = *(const float4*)&rwlds[4 * ((q0 + 1) ^ key)];
                float xs = xa[cc];
                pe[0] += xs * w0.x; pe[1] += xs * w0.y;
                pe[2] += xs * w0.z; pe[3] += xs * w0.w;
                pe[4] += xs * w1.x; pe[5] += xs * w1.y;
                pe[6] += xs * w1.z; pe[7] += xs * w1.w;
            }
        }
        // wave butterfly -> lane 0 holds full logit sums
#pragma unroll
        for (int s = 1; s < 64; s <<= 1)
#pragma unroll
            for (int e2 = 0; e2 < 8; ++e2) pe[e2] += __shfl_xor(pe[e2], s);
        if (lane == 0) {
            float m = pe[0] + rb[0]; int bi = 0;
#pragma unroll
            for (int e2 = 1; e2 < 8; ++e2) {     // first-max tie-break (strict >)
                float l = pe[e2] + rb[e2];
                if (l > m) { m = l; bi = e2; }
            }
            float sum = 0.f;
#pragma unroll
            for (int e2 = 0; e2 < 8; ++e2) sum += __expf(pe[e2] + rb[e2] - m);
            gate[t] = 1.0f / sum;                // softmax prob at argmax
            idx[t]  = bi;
        }
    }
}

// ---------------- K2: rank/permutation (narrow: 32 blocks — atomics are cheap here) ---
// One token/thread. Block-local LDS histogram -> local rank; ONE global atomic per
// (block, expert) on 128B-padded lines (256 total). Last block builds m-tile table.
__global__ __launch_bounds__(256) void k_rank(const int* __restrict__ idx,
                                              int* __restrict__ perm2,
                                              int* __restrict__ cnt,
                                              int* __restrict__ done,
                                              int* __restrict__ tile_e,
                                              int* __restrict__ tile_row) {
    __shared__ int lcnt[kE];
    __shared__ int lbase[kE];
    int tid = threadIdx.x;
    if (tid < kE) lcnt[tid] = 0;
    __syncthreads();
    int t = blockIdx.x * 256 + tid;
    int bi = idx[t];
    int lrank = atomicAdd(&lcnt[bi], 1);        // LDS atomic: local rank
    __syncthreads();
    if (tid < kE) lbase[tid] = atomicAdd(&cnt[tid * kCntStride], lcnt[tid]);
    __syncthreads();
    perm2[bi * kT + lbase[bi] + lrank] = t;     // sorted row -> token
    __syncthreads();
    if (tid == 0) {
        __threadfence();
        int old = atomicAdd(done, 1);
        if (old == (int)gridDim.x - 1) {
            __threadfence();
            int tt = 0;
            for (int ee = 0; ee < kE; ++ee) {
                int c = atomicAdd(&cnt[ee * kCntStride], 0);   // device-coherent read
                int nt = (c + 127) >> 7;
                for (int i = 0; i < nt; ++i) { tile_e[tt] = ee; tile_row[tt] = i << 7; ++tt; }
            }
            for (; tt < kMaxTiles; ++tt) tile_e[tt] = -1;
        }
    }
}

// ---------------- K3: grouped GEMM, 128x128 tile, BK=64, mfma_f32_16x16x32_bf16 --------
// A-tiles are gathered ON THE FLY from xb via perm2 (per-lane global addresses into
// global_load_lds; LDS dest stays uniform-base+lane*16). Pad rows (>= cnt[e]) read
// token 0 and are skipped in the epilogue — no zero-fill pass, no gathered A array.
// Staging rows are 128 B (8 x 16B chunks) with chunk-XOR swizzle on the GLOBAL side
// (LDS[r][s] = G[r][s^(r&7)]); fragment reads un-swizzle with sw = (g^(l15&7)).
// __launch_bounds__(256,3) -> 3 blocks/CU (96KB LDS): all 576 blocks co-resident in
// ONE round and wave-level overlap hides the barrier drain (m114). Per-ks fragment
// loads keep live frag VGPRs at 32 to fit the 3-wave budget without spills.
constexpr int kBK = 64;

__global__ __launch_bounds__(256, 3) void k_gemm(const unsigned short* __restrict__ xb,
                                                 const unsigned short* __restrict__ Wt,
                                                 const float* __restrict__ eb,
                                                 const int* __restrict__ perm2,
                                                 const float* __restrict__ gate,
                                                 const int* __restrict__ cnt,
                                                 const int* __restrict__ tile_e,
                                                 const int* __restrict__ tile_row,
                                                 float* __restrict__ out) {
    int bm = blockIdx.x, bn = blockIdx.y;
    int e = tile_e[bm];
    if (e < 0) return;
    int l0 = tile_row[bm];                       // expert-local row base
    int ce = cnt[e * kCntStride];
    const int* pe = perm2 + e * kT;

    __shared__ __align__(16) unsigned short As[128 * kBK];   // 16 KB
    __shared__ __align__(16) unsigned short Bs[128 * kBK];   // 16 KB

    int tid = threadIdx.x;
    int wave = tid >> 6, lane = tid & 63;
    int wm = wave & 1, wn = wave >> 1;           // 2x2 waves over 128x128
    int quad = lane >> 4, l15 = lane & 15;

    floatx4 acc[4][4];
#pragma unroll
    for (int i = 0; i < 4; ++i)
#pragma unroll
        for (int j = 0; j < 4; ++j) acc[i][j] = floatx4{0.f, 0.f, 0.f, 0.f};

    // staging: wave stages rows [wave*32, wave*32+32), 4 issues of 8 rows each.
    int lrow8 = lane >> 3;                       // 0..7
    int lseg8 = (lane & 7) ^ lrow8;              // swizzled 16B chunk (global side)
    const unsigned short* aPj[4];
#pragma unroll
    for (int j = 0; j < 4; ++j) {
        int lr = l0 + wave * 32 + j * 8 + lrow8;
        int tok = (lr < ce) ? pe[lr] : 0;        // pad rows read token 0, skipped later
        aPj[j] = xb + (size_t)tok * kH + lseg8 * 8;
    }
    const unsigned short* bP = Wt + ((size_t)e << 20)
                             + (size_t)(bn * 128 + wave * 32 + lrow8) * kH + lseg8 * 8;
    unsigned short* lA = &As[(wave * 32) * kBK];
    unsigned short* lB = &Bs[(wave * 32) * kBK];

    for (int k0 = 0; k0 < kH; k0 += kBK) {
        __syncthreads();                         // prior iter's fragment reads complete
#pragma unroll
        for (int j = 0; j < 4; ++j) {
            GLDS16(aPj[j] + k0, lA + j * 8 * kBK);
            GLDS16(bP + (size_t)(j * 8) * kH + k0, lB + j * 8 * kBK);
        }
        __syncthreads();                         // drains vmcnt -> tile visible

        // fragment read chunk: global seg g = ks*4+quad at row l15 -> LDS seg g^(l15&7)
#pragma unroll
        for (int ks = 0; ks < 2; ++ks) {
            int sw = ((ks * 4 + quad) ^ (l15 & 7)) * 8;
            short8 af[4], bf[4];
#pragma unroll
            for (int i = 0; i < 4; ++i)
                af[i] = *(const short8*)&As[(wm * 64 + i * 16 + l15) * kBK + sw];
#pragma unroll
            for (int j = 0; j < 4; ++j)
                bf[j] = *(const short8*)&Bs[(wn * 64 + j * 16 + l15) * kBK + sw];
#pragma unroll
            for (int i = 0; i < 4; ++i)
#pragma unroll
                for (int j = 0; j < 4; ++j)
                    acc[i][j] = __builtin_amdgcn_mfma_f32_16x16x32_bf16(af[i], bf[j],
                                                                        acc[i][j], 0, 0, 0);
        }
    }

    // epilogue: C row = quad*4 + reg, col = lane&15 (verified m89/m91 mapping)
    int colbase = bn * 128 + wn * 64;
#pragma unroll
    for (int i = 0; i < 4; ++i) {
        int rl = l0 + wm * 64 + i * 16 + quad * 4;
#pragma unroll
        for (int rg = 0; rg < 4; ++rg) {
            int lr = rl + rg;
            if (lr >= ce) continue;         // pad row
            int tok = pe[lr];
            float g = gate[tok];
            float* op = out + (size_t)tok * kH;
#pragma unroll
            for (int j = 0; j < 4; ++j) {
                int col = colbase + j * 16 + l15;
                op[col] = g * (acc[i][j][rg] + eb[e * kH + col]);
            }
        }
    }
}

extern "C" void kernel_launch(void* const* d_in, const int* in_sizes, int n_in,
                              void* d_out, int out_size, void* d_ws, size_t ws_size,
                              hipStream_t stream) {
    const float* x  = (const float*)d_in[0];   // [T,H]
    const float* rw = (const float*)d_in[1];   // [H,E]
    const float* rb = (const float*)d_in[2];   // [E]
    const float* ew = (const float*)d_in[3];   // [E,H,H]
    const float* eb = (const float*)d_in[4];   // [E,H]
    float* out = (float*)d_out;                // [T,H]

    char* p = (char*)d_ws;
    unsigned short* Wt = (unsigned short*)p; p += (size_t)kE * kH * kH * 2;   // 16 MB
    unsigned short* xb = (unsigned short*)p; p += (size_t)kT * kH * 2;        // 16 MB
    float* gate  = (float*)p; p += (size_t)kT * 4;
    int* idx     = (int*)p;   p += (size_t)kT * 4;
    int* perm2   = (int*)p;   p += (size_t)kE * kT * 4;                       // 256 KB
    int* cnt     = (int*)p;   p += kE * kCntStride * 4;   // 128B-padded counters
    int* done    = (int*)p;   p += 64;
    int* tile_e  = (int*)p;   p += kMaxTiles * 4;
    int* tile_r  = (int*)p;   p += kMaxTiles * 4;

    k_prep<<<2048, 256, 0, stream>>>(ew, Wt, x, xb, rw, rb, gate, idx, cnt, done);
    k_rank<<<kT / 256, 256, 0, stream>>>(idx, perm2, cnt, done, tile_e, tile_r);
    dim3 gg(kMaxTiles, kH / 128);
    k_gemm<<<gg, 256, 0, stream>>>(xb, Wt, eb, perm2, gate, cnt, tile_e, tile_r, out);
}

// Round 7
// 156.287 us; speedup vs baseline: 1.0656x; 1.0656x over previous
//
#include <hip/hip_runtime.h>

// Problem constants (B=4, S=2048 -> T=8192 tokens; H=1024; E=8 experts)
constexpr int kT = 8192;
constexpr int kH = 1024;
constexpr int kE = 8;
constexpr int kMaxTiles = 72;     // kT/128 + kE
constexpr int kCntStride = 32;    // pad expert counters to separate 128B cache lines

typedef short short8 __attribute__((ext_vector_type(8)));
typedef float floatx4 __attribute__((ext_vector_type(4)));

__device__ inline unsigned short f2b(float f) {
    union { float f; unsigned int u; } v; v.f = f;
    unsigned int r = v.u + 0x7FFFu + ((v.u >> 16) & 1u);  // round-to-nearest-even
    return (unsigned short)(r >> 16);
}

#define GLDS16(gp, lp)                                                                  \
    __builtin_amdgcn_global_load_lds(                                                   \
        (const __attribute__((address_space(1))) unsigned int*)(gp),                    \
        (__attribute__((address_space(3))) unsigned int*)(lp), 16, 0, 0)

// ---------------- K1: FUSED prep (R14) ----------------
// Range-split (R3 ordering — parity interleave of R13 regressed): bid [0,1024) =
// transpose, [1024,2048) = router. R14 fixes the transpose's scalar-LDS defect:
// old phase-2 did 32x ds_read_u16/thread (~190cyc issue). New scheme is wide on
// BOTH sides: k-pairs packed to dwords; LDS is [128 n][32 dw] with XOR swizzle
// phys = p ^ (((n^(n>>3))&7)<<2)  (key 4-dw-aligned so b128 stays contiguous:
// (P|d)^key = p0+d). Writes: ONE ds_write_b128 per column (4/thread). Reads:
// 4x ds_read_b128/thread. Both sides verified to hit all 8 four-bank groups.
//   router: rw (32KB) staged once in LDS (16-B chunk-XOR swizzle, R10 fix for
//   TA-request amplification); fused convert+router, 8 tokens/block.
__global__ __launch_bounds__(256) void k_prep(const float* __restrict__ W,
                                              unsigned short* __restrict__ Wt,
                                              const float* __restrict__ x,
                                              unsigned short* __restrict__ xb,
                                              const float* __restrict__ rw,
                                              const float* __restrict__ rb,
                                              float* __restrict__ gate,
                                              int* __restrict__ idx,
                                              int* __restrict__ cnt,
                                              int* __restrict__ done) {
    __shared__ __align__(16) char smem[32768];
    int bid = blockIdx.x, tid = threadIdx.x;
    if (bid == 0 && tid < kE + 1) {              // zero padded cnt[] and done flag
        if (tid < kE) cnt[tid * kCntStride] = 0; else *done = 0;
    }
    if (bid < 1024) {
        // ---- transpose path: 64k x 128n per block ----
        unsigned int* ldsw = (unsigned int*)smem;   // [128][32] dwords, swizzled (16KB)
        int tb = bid;
        int e = tb >> 7, kb = (tb >> 3) & 15, nb2 = tb & 7;
        const float* Wp = W + ((size_t)e << 20) + (size_t)(kb * 64) * kH + nb2 * 128;
        int c = (tid & 31) * 4;                  // n base (0..124)
        int rr = tid >> 5;                       // 0..7 (8-k slab)
        unsigned int dw[4][4];                   // [i = k-pair][j = n offset]
#pragma unroll
        for (int i = 0; i < 4; ++i) {
            int r0 = rr * 8 + i * 2;
            float4 v0 = *(const float4*)(Wp + (size_t)r0 * kH + c);
            float4 v1 = *(const float4*)(Wp + (size_t)(r0 + 1) * kH + c);
            dw[i][0] = (unsigned int)f2b(v0.x) | ((unsigned int)f2b(v1.x) << 16);
            dw[i][1] = (unsigned int)f2b(v0.y) | ((unsigned int)f2b(v1.y) << 16);
            dw[i][2] = (unsigned int)f2b(v0.z) | ((unsigned int)f2b(v1.z) << 16);
            dw[i][3] = (unsigned int)f2b(v0.w) | ((unsigned int)f2b(v1.w) << 16);
        }
#pragma unroll
        for (int j = 0; j < 4; ++j) {
            int n = c + j;
            int key = ((n ^ (n >> 3)) & 7) << 2;
            uint4 q{dw[0][j], dw[1][j], dw[2][j], dw[3][j]};   // logical dw rr*4..+3
            *(uint4*)&ldsw[n * 32 + ((rr * 4) ^ key)] = q;     // ds_write_b128
        }
        __syncthreads();
        unsigned short* Wo = Wt + ((size_t)e << 20) + (size_t)(nb2 * 128) * kH + kb * 64;
        int k8 = (tid & 7) * 8;                  // this thread's 8-k chunk
#pragma unroll
        for (int pp = 0; pp < 4; ++pp) {
            int n = pp * 32 + (tid >> 3);        // 0..127 (output row)
            int key = ((n ^ (n >> 3)) & 7) << 2;
            uint4 q = *(const uint4*)&ldsw[n * 32 + (((tid & 7) * 4) ^ key)];
            *(uint4*)(Wo + (size_t)n * kH + k8) = q;   // short8, k-contiguous 16B
        }
        return;
    }
    // ---- router path: rid in 0..1023, 8 tokens/block (2 per wave) ----
    float* rwlds = (float*)smem;                 // 2048 16-B chunks
    int rid = bid - 1024;
    // stage rw -> LDS, chunk-XOR swizzled; global side dense (16 B/lane contiguous)
#pragma unroll
    for (int i = 0; i < 8; ++i) {
        int g = i * 256 + tid;                   // logical 16-B chunk id
        float4 v = *(const float4*)(rw + 4 * g);
        int pq = g ^ ((g >> 3) & 7);
        *(float4*)&rwlds[4 * pq] = v;
    }
    __syncthreads();
    int w = tid >> 6, lane = tid & 63;
    for (int tk = 0; tk < 2; ++tk) {
        int t = rid * 8 + w * 2 + tk;
        const float* xp = x + (size_t)t * kH;
        unsigned short* xop = xb + (size_t)t * kH;
        float pe[8];
#pragma unroll
        for (int e2 = 0; e2 < 8; ++e2) pe[e2] = 0.f;
#pragma unroll
        for (int j = 0; j < 4; ++j) {
            int h0 = j * 256 + lane * 4;
            float4 xv = *(const float4*)(xp + h0);
            ushort4 o;
            o.x = f2b(xv.x); o.y = f2b(xv.y); o.z = f2b(xv.z); o.w = f2b(xv.w);
            *(ushort4*)(xop + h0) = o;
            float xa[4] = {xv.x, xv.y, xv.z, xv.w};
#pragma unroll
            for (int cc = 0; cc < 4; ++cc) {
                int q0 = 2 * (h0 + cc);          // even chunk of rw row h
                int key = (q0 >> 3) & 7;         // = lane&7 (write-side function match)
                float4 w0 = *(const float4*)&rwlds[4 * (q0 ^ key)];
                float4 w1 = *(const float4*)&rwlds[4 * ((q0 + 1) ^ key)];
                float xs = xa[cc];
                pe[0] += xs * w0.x; pe[1] += xs * w0.y;
                pe[2] += xs * w0.z; pe[3] += xs * w0.w;
                pe[4] += xs * w1.x; pe[5] += xs * w1.y;
                pe[6] += xs * w1.z; pe[7] += xs * w1.w;
            }
        }
        // wave butterfly -> lane 0 holds full logit sums
#pragma unroll
        for (int s = 1; s < 64; s <<= 1)
#pragma unroll
            for (int e2 = 0; e2 < 8; ++e2) pe[e2] += __shfl_xor(pe[e2], s);
        if (lane == 0) {
            float m = pe[0] + rb[0]; int bi = 0;
#pragma unroll
            for (int e2 = 1; e2 < 8; ++e2) {     // first-max tie-break (strict >)
                float l = pe[e2] + rb[e2];
                if (l > m) { m = l; bi = e2; }
            }
            float sum = 0.f;
#pragma unroll
            for (int e2 = 0; e2 < 8; ++e2) sum += __expf(pe[e2] + rb[e2] - m);
            gate[t] = 1.0f / sum;                // softmax prob at argmax
            idx[t]  = bi;
        }
    }
}

// ---------------- K2: rank/permutation (narrow: 32 blocks — atomics are cheap here) ---
// One token/thread. Block-local LDS histogram -> local rank; ONE global atomic per
// (block, expert) on 128B-padded lines (256 total). Last block builds m-tile table.
__global__ __launch_bounds__(256) void k_rank(const int* __restrict__ idx,
                                              int* __restrict__ perm2,
                                              int* __restrict__ cnt,
                                              int* __restrict__ done,
                                              int* __restrict__ tile_e,
                                              int* __restrict__ tile_row) {
    __shared__ int lcnt[kE];
    __shared__ int lbase[kE];
    int tid = threadIdx.x;
    if (tid < kE) lcnt[tid] = 0;
    __syncthreads();
    int t = blockIdx.x * 256 + tid;
    int bi = idx[t];
    int lrank = atomicAdd(&lcnt[bi], 1);        // LDS atomic: local rank
    __syncthreads();
    if (tid < kE) lbase[tid] = atomicAdd(&cnt[tid * kCntStride], lcnt[tid]);
    __syncthreads();
    perm2[bi * kT + lbase[bi] + lrank] = t;     // sorted row -> token
    __syncthreads();
    if (tid == 0) {
        __threadfence();
        int old = atomicAdd(done, 1);
        if (old == (int)gridDim.x - 1) {
            __threadfence();
            int tt = 0;
            for (int ee = 0; ee < kE; ++ee) {
                int c = atomicAdd(&cnt[ee * kCntStride], 0);   // device-coherent read
                int nt = (c + 127) >> 7;
                for (int i = 0; i < nt; ++i) { tile_e[tt] = ee; tile_row[tt] = i << 7; ++tt; }
            }
            for (; tt < kMaxTiles; ++tt) tile_e[tt] = -1;
        }
    }
}

// ---------------- K3: grouped GEMM, 128x128 tile, BK=64, mfma_f32_16x16x32_bf16 --------
// A-tiles are gathered ON THE FLY from xb via perm2 (per-lane global addresses into
// global_load_lds; LDS dest stays uniform-base+lane*16). Pad rows (>= cnt[e]) read
// token 0 and are skipped in the epilogue — no zero-fill pass, no gathered A array.
// Staging rows are 128 B (8 x 16B chunks) with chunk-XOR swizzle on the GLOBAL side
// (LDS[r][s] = G[r][s^(r&7)]); fragment reads un-swizzle with sw = (g^(l15&7)).
// __launch_bounds__(256,3) -> 3 blocks/CU (96KB LDS): all 576 blocks co-resident in
// ONE round and wave-level overlap hides the barrier drain (m114). Per-ks fragment
// loads keep live frag VGPRs at 32 to fit the 3-wave budget without spills.
constexpr int kBK = 64;

__global__ __launch_bounds__(256, 3) void k_gemm(const unsigned short* __restrict__ xb,
                                                 const unsigned short* __restrict__ Wt,
                                                 const float* __restrict__ eb,
                                                 const int* __restrict__ perm2,
                                                 const float* __restrict__ gate,
                                                 const int* __restrict__ cnt,
                                                 const int* __restrict__ tile_e,
                                                 const int* __restrict__ tile_row,
                                                 float* __restrict__ out) {
    int bm = blockIdx.x, bn = blockIdx.y;
    int e = tile_e[bm];
    if (e < 0) return;
    int l0 = tile_row[bm];                       // expert-local row base
    int ce = cnt[e * kCntStride];
    const int* pe = perm2 + e * kT;

    __shared__ __align__(16) unsigned short As[128 * kBK];   // 16 KB
    __shared__ __align__(16) unsigned short Bs[128 * kBK];   // 16 KB

    int tid = threadIdx.x;
    int wave = tid >> 6, lane = tid & 63;
    int wm = wave & 1, wn = wave >> 1;           // 2x2 waves over 128x128
    int quad = lane >> 4, l15 = lane & 15;

    floatx4 acc[4][4];
#pragma unroll
    for (int i = 0; i < 4; ++i)
#pragma unroll
        for (int j = 0; j < 4; ++j) acc[i][j] = floatx4{0.f, 0.f, 0.f, 0.f};

    // staging: wave stages rows [wave*32, wave*32+32), 4 issues of 8 rows each.
    int lrow8 = lane >> 3;                       // 0..7
    int lseg8 = (lane & 7) ^ lrow8;              // swizzled 16B chunk (global side)
    const unsigned short* aPj[4];
#pragma unroll
    for (int j = 0; j < 4; ++j) {
        int lr = l0 + wave * 32 + j * 8 + lrow8;
        int tok = (lr < ce) ? pe[lr] : 0;        // pad rows read token 0, skipped later
        aPj[j] = xb + (size_t)tok * kH + lseg8 * 8;
    }
    const unsigned short* bP = Wt + ((size_t)e << 20)
                             + (size_t)(bn * 128 + wave * 32 + lrow8) * kH + lseg8 * 8;
    unsigned short* lA = &As[(wave * 32) * kBK];
    unsigned short* lB = &Bs[(wave * 32) * kBK];

    for (int k0 = 0; k0 < kH; k0 += kBK) {
        __syncthreads();                         // prior iter's fragment reads complete
#pragma unroll
        for (int j = 0; j < 4; ++j) {
            GLDS16(aPj[j] + k0, lA + j * 8 * kBK);
            GLDS16(bP + (size_t)(j * 8) * kH + k0, lB + j * 8 * kBK);
        }
        __syncthreads();                         // drains vmcnt -> tile visible

        // fragment read chunk: global seg g = ks*4+quad at row l15 -> LDS seg g^(l15&7)
#pragma unroll
        for (int ks = 0; ks < 2; ++ks) {
            int sw = ((ks * 4 + quad) ^ (l15 & 7)) * 8;
            short8 af[4], bf[4];
#pragma unroll
            for (int i = 0; i < 4; ++i)
                af[i] = *(const short8*)&As[(wm * 64 + i * 16 + l15) * kBK + sw];
#pragma unroll
            for (int j = 0; j < 4; ++j)
                bf[j] = *(const short8*)&Bs[(wn * 64 + j * 16 + l15) * kBK + sw];
#pragma unroll
            for (int i = 0; i < 4; ++i)
#pragma unroll
                for (int j = 0; j < 4; ++j)
                    acc[i][j] = __builtin_amdgcn_mfma_f32_16x16x32_bf16(af[i], bf[j],
                                                                        acc[i][j], 0, 0, 0);
        }
    }

    // epilogue: C row = quad*4 + reg, col = lane&15 (verified m89/m91 mapping)
    int colbase = bn * 128 + wn * 64;
#pragma unroll
    for (int i = 0; i < 4; ++i) {
        int rl = l0 + wm * 64 + i * 16 + quad * 4;
#pragma unroll
        for (int rg = 0; rg < 4; ++rg) {
            int lr = rl + rg;
            if (lr >= ce) continue;         // pad row
            int tok = pe[lr];
            float g = gate[tok];
            float* op = out + (size_t)tok * kH;
#pragma unroll
            for (int j = 0; j < 4; ++j) {
                int col = colbase + j * 16 + l15;
                op[col] = g * (acc[i][j][rg] + eb[e * kH + col]);
            }
        }
    }
}

extern "C" void kernel_launch(void* const* d_in, const int* in_sizes, int n_in,
                              void* d_out, int out_size, void* d_ws, size_t ws_size,
                              hipStream_t stream) {
    const float* x  = (const float*)d_in[0];   // [T,H]
    const float* rw = (const float*)d_in[1];   // [H,E]
    const float* rb = (const float*)d_in[2];   // [E]
    const float* ew = (const float*)d_in[3];   // [E,H,H]
    const float* eb = (const float*)d_in[4];   // [E,H]
    float* out = (float*)d_out;                // [T,H]

    char* p = (char*)d_ws;
    unsigned short* Wt = (unsigned short*)p; p += (size_t)kE * kH * kH * 2;   // 16 MB
    unsigned short* xb = (unsigned short*)p; p += (size_t)kT * kH * 2;        // 16 MB
    float* gate  = (float*)p; p += (size_t)kT * 4;
    int* idx     = (int*)p;   p += (size_t)kT * 4;
    int* perm2   = (int*)p;   p += (size_t)kE * kT * 4;                       // 256 KB
    int* cnt     = (int*)p;   p += kE * kCntStride * 4;   // 128B-padded counters
    int* done    = (int*)p;   p += 64;
    int* tile_e  = (int*)p;   p += kMaxTiles * 4;
    int* tile_r  = (int*)p;   p += kMaxTiles * 4;

    k_prep<<<2048, 256, 0, stream>>>(ew, Wt, x, xb, rw, rb, gate, idx, cnt, done);
    k_rank<<<kT / 256, 256, 0, stream>>>(idx, perm2, cnt, done, tile_e, tile_r);
    dim3 gg(kMaxTiles, kH / 128);
    k_gemm<<<gg, 256, 0, stream>>>(xb, Wt, eb, perm2, gate, cnt, tile_e, tile_r, out);
}